// Round 5
// baseline (53.255 us; speedup 1.0000x reference)
//
#include <hip/hip_runtime.h>

#define NBINS 10
#define TPB 256
#define NCOPY 32
#define CSTR 17                      // 17*c mod 32 is a bank bijection
#define LDSN (NCOPY * CSTR)          // 544 ints
#define SCALE 1048576.0f             // 2^20 fixed-point scale
#define INV_SCALE (1.0f / 1048576.0f)
#define BATCH 8                      // 8 float4 per array per thread per batch

typedef float f32x4 __attribute__((ext_vector_type(4)));

// Pass 1: histogram of fixed-point d = u-e into per-block LDS (native
// ds_add_u32 fire-and-forget atomics), per-block float partials -> part[].
__global__ __launch_bounds__(TPB) void uce_hist(const float* __restrict__ up,
                                                const float* __restrict__ ep,
                                                float* __restrict__ part, int n4) {
    __shared__ int h[LDSN];
    int tid = threadIdx.x;
    for (int i = tid; i < LDSN; i += TPB) h[i] = 0;
    __syncthreads();

    int cbase = (tid & (NCOPY - 1)) * CSTR;

    auto proc1 = [&](float u, float e) {
        // FROZEN binning (bit-exact vs reference, absmax 0.0 in R0-R3):
        // bin i iff fl(i*0.1f) < u <= fl((i+1)*0.1f)
        int g = (int)(u * 10.0f);
        g = g > 9 ? 9 : g;
        float gf = (float)g;
        float lo = gf * 0.1f;
        float hi = (gf + 1.0f) * 0.1f;
        g += (u > hi) ? 1 : 0;             // mutually exclusive fixups
        g -= (u <= lo) ? 1 : 0;            // u<=0 -> -1; u>1 -> 10
        int slot = g & 15;                 // -1->15, 10->10: scratch, never read
        int v = (int)rintf((u - e) * SCALE);
        atomicAdd(&h[cbase + slot], v);    // ds_add_u32, no return -> no stall
    };
    auto proc4 = [&](f32x4 uu, f32x4 ee) {
        proc1(uu.x, ee.x); proc1(uu.y, ee.y);
        proc1(uu.z, ee.z); proc1(uu.w, ee.w);
    };

    const f32x4* __restrict__ u4 = (const f32x4*)up;
    const f32x4* __restrict__ e4 = (const f32x4*)ep;
    int base = blockIdx.x * TPB + tid;
    int T = gridDim.x * TPB;
    int nb = n4 / (BATCH * T);           // full batches (exact for N=2^25)

    for (int it = 0; it < nb; ++it) {
        int i0 = base + it * BATCH * T;
        f32x4 U[BATCH], E[BATCH];
        // Issue all 16 loads back-to-back (256 B/lane in flight), then pin
        // them live so regalloc can't serialize into load->use pairs.
#pragma unroll
        for (int b = 0; b < BATCH; ++b) U[b] = u4[i0 + b * T];
#pragma unroll
        for (int b = 0; b < BATCH; ++b) E[b] = e4[i0 + b * T];
#pragma unroll
        for (int b = 0; b < BATCH; ++b) {
            asm volatile("" : "+v"(U[b]), "+v"(E[b]));
        }
#pragma unroll
        for (int b = 0; b < BATCH; ++b) proc4(U[b], E[b]);
    }
    for (int i = base + nb * BATCH * T; i < n4; i += T) {  // tail (empty here)
        proc4(u4[i], e4[i]);
    }
    __syncthreads();

    if (tid < NBINS) {
        int s = 0;
#pragma unroll
        for (int c = 0; c < NCOPY; ++c) s += h[c * CSTR + tid];
        part[blockIdx.x * NBINS + tid] = (float)s * INV_SCALE;
    }
}

// Pass 2: reduce per-block partials, UCE = (1/n) * sum_b |S_b|
__global__ __launch_bounds__(TPB) void uce_final(const float* __restrict__ part,
                                                 float* __restrict__ out,
                                                 int nblocks, float inv_n) {
    float s[NBINS];
#pragma unroll
    for (int b = 0; b < NBINS; ++b) s[b] = 0.0f;
    int tid = threadIdx.x;
    for (int j = tid; j < nblocks; j += TPB) {
        const float* p = part + j * NBINS;
#pragma unroll
        for (int b = 0; b < NBINS; ++b) s[b] += p[b];
    }
#pragma unroll
    for (int b = 0; b < NBINS; ++b) {
#pragma unroll
        for (int off = 32; off > 0; off >>= 1) s[b] += __shfl_down(s[b], off, 64);
    }
    __shared__ float sm[4][NBINS];
    int w = tid >> 6, lane = tid & 63;
    if (lane == 0) {
#pragma unroll
        for (int b = 0; b < NBINS; ++b) sm[w][b] = s[b];
    }
    __syncthreads();
    if (tid == 0) {
        float uce = 0.0f;
#pragma unroll
        for (int b = 0; b < NBINS; ++b) {
            float t = sm[0][b] + sm[1][b] + sm[2][b] + sm[3][b];
            uce += fabsf(t);
        }
        out[0] = uce * inv_n;
    }
}

extern "C" void kernel_launch(void* const* d_in, const int* in_sizes, int n_in,
                              void* d_out, int out_size, void* d_ws, size_t ws_size,
                              hipStream_t stream) {
    const float* u = (const float*)d_in[0];
    const float* e = (const float*)d_in[1];
    float* part = (float*)d_ws;          // 2048*10 floats = 80 KB scratch
    float* out = (float*)d_out;
    int n = in_sizes[0];
    int n4 = n >> 2;
    const int NB = 2048;                 // 8 blocks/CU

    uce_hist<<<NB, TPB, 0, stream>>>(u, e, part, n4);
    uce_final<<<1, TPB, 0, stream>>>(part, out, NB, 1.0f / (float)n);
}